// Round 1
// baseline (460.607 us; speedup 1.0000x reference)
//
#include <hip/hip_runtime.h>

#define NBLOCKS 4096
#define WPB 4                          // waves per block
#define BTOT 262144
#define SPW (BTOT / (NBLOCKS * WPB))   // 16 samples per wave

// tanh(a) and sech^2(a) from one exp + one rcp, saturation-safe.
__device__ __forceinline__ void tanh_sech2(float a, float& h, float& g) {
    float ac = fminf(fmaxf(a, -15.f), 15.f);
    float E = __expf(2.f * ac);                 // e^{2a}
    float inv = __builtin_amdgcn_rcpf(E + 1.f); // 1/(e^{2a}+1)
    h = 1.f - 2.f * inv;                        // tanh(a)
    g = 4.f * E * inv * inv;                    // sech^2(a) = 1 - h^2
}

// matvec over the 5 broadcast state vectors with per-lane weight column wcol[]
#define MATVEC(wcol, bj)                                                        \
    av = (bj); ax = 0.f; ay = 0.f; az = 0.f; as_ = 0.f;                         \
    _Pragma("unroll")                                                           \
    for (int ib = 0; ib < 16; ++ib) {                                           \
        const float4 hv = *(const float4*)&st[wv][0][ib * 4];                   \
        const float4 xv = *(const float4*)&st[wv][1][ib * 4];                   \
        const float4 yv = *(const float4*)&st[wv][2][ib * 4];                   \
        const float4 zv = *(const float4*)&st[wv][3][ib * 4];                   \
        const float4 sv = *(const float4*)&st[wv][4][ib * 4];                   \
        const float w0 = wcol[ib*4+0], w1 = wcol[ib*4+1],                       \
                    w2 = wcol[ib*4+2], w3 = wcol[ib*4+3];                       \
        av += hv.x*w0 + hv.y*w1 + hv.z*w2 + hv.w*w3;                            \
        ax += xv.x*w0 + xv.y*w1 + xv.z*w2 + xv.w*w3;                            \
        ay += yv.x*w0 + yv.y*w1 + yv.z*w2 + yv.w*w3;                            \
        az += zv.x*w0 + zv.y*w1 + zv.z*w2 + zv.w*w3;                            \
        as_ += sv.x*w0 + sv.y*w1 + sv.z*w2 + sv.w*w3;                           \
    }

__global__ __launch_bounds__(256, 2) void pinn_div_kernel(
    const float* __restrict__ x_r, const float* __restrict__ sigma_r,
    const float* __restrict__ W1, const float* __restrict__ b1,
    const float* __restrict__ W2, const float* __restrict__ b2,
    const float* __restrict__ W3, const float* __restrict__ b3,
    const float* __restrict__ W4, float* __restrict__ out)
{
    __shared__ float st[WPB][5][64];
    const int lane = threadIdx.x & 63;
    const int wv = threadIdx.x >> 6;

    // Per-lane constants: weight COLUMNS in VGPRs (loaded coalesced by row).
    float w2c[64], w3c[64];
#pragma unroll
    for (int i = 0; i < 64; ++i) w2c[i] = W2[i * 64 + lane];
#pragma unroll
    for (int i = 0; i < 64; ++i) w3c[i] = W3[i * 64 + lane];
    const float w1x = W1[lane], w1y = W1[64 + lane], w1z = W1[128 + lane];
    const float b1j = b1[lane], b2j = b2[lane], b3j = b3[lane];
    const float w4j = W4[lane];
    const float q1 = w1x * w1x + w1y * w1y + w1z * w1z;  // sum_d (a1'_d)^2

    const long wave_global = (long)blockIdx.x * WPB + wv;
    const long sbase = wave_global * SPW;

    for (int t = 0; t < SPW; ++t) {
        const long s = sbase + t;
        const float x0 = x_r[s * 3 + 0];
        const float x1 = x_r[s * 3 + 1];
        const float x2 = x_r[s * 3 + 2];
        const float sg = sigma_r[s];

        // ---- layer 1 (input dim 3; a1'_d = W1[d,:], a1'' = 0) ----
        float h, g;
        tanh_sech2(x0 * w1x + x1 * w1y + x2 * w1z + b1j, h, g);
        float dx = g * w1x, dy = g * w1y, dz = g * w1z;
        float ss = -2.f * h * g * q1;

        float av, ax, ay, az, as_;

        // ---- layer 2 ----
        st[wv][0][lane] = h;  st[wv][1][lane] = dx; st[wv][2][lane] = dy;
        st[wv][3][lane] = dz; st[wv][4][lane] = ss;
        __syncthreads();
        MATVEC(w2c, b2j);
        __syncthreads();
        tanh_sech2(av, h, g);
        dx = g * ax; dy = g * ay; dz = g * az;
        ss = g * as_ - 2.f * h * g * (ax * ax + ay * ay + az * az);

        // ---- layer 3 ----
        st[wv][0][lane] = h;  st[wv][1][lane] = dx; st[wv][2][lane] = dy;
        st[wv][3][lane] = dz; st[wv][4][lane] = ss;
        __syncthreads();
        MATVEC(w3c, b3j);
        __syncthreads();
        tanh_sech2(av, h, g);
        ss = g * as_ - 2.f * h * g * (ax * ax + ay * ay + az * az);

        // ---- output: sigma * (s3 . W4) ----
        float c = ss * w4j;
        c += __shfl_xor(c, 32);
        c += __shfl_xor(c, 16);
        c += __shfl_xor(c, 8);
        c += __shfl_xor(c, 4);
        c += __shfl_xor(c, 2);
        c += __shfl_xor(c, 1);
        if (lane == 0) out[s] = sg * c;
    }
}

extern "C" void kernel_launch(void* const* d_in, const int* in_sizes, int n_in,
                              void* d_out, int out_size, void* d_ws, size_t ws_size,
                              hipStream_t stream) {
    const float* x_r     = (const float*)d_in[0];
    const float* sigma_r = (const float*)d_in[1];
    const float* W1      = (const float*)d_in[2];
    const float* b1      = (const float*)d_in[3];
    const float* W2      = (const float*)d_in[4];
    const float* b2      = (const float*)d_in[5];
    const float* W3      = (const float*)d_in[6];
    const float* b3      = (const float*)d_in[7];
    const float* W4      = (const float*)d_in[8];
    float* out = (float*)d_out;

    pinn_div_kernel<<<NBLOCKS, 256, 0, stream>>>(
        x_r, sigma_r, W1, b1, W2, b2, W3, b3, W4, out);
}

// Round 2
// 398.220 us; speedup vs baseline: 1.1567x; 1.1567x over previous
//
#include <hip/hip_runtime.h>

#define NBLOCKS 4096
#define WPB 4                          // waves per block
#define BTOT 262144
#define SPW (BTOT / (NBLOCKS * WPB))   // 16 samples per wave

// tanh(a) and sech^2(a) from one exp + one rcp, saturation-safe.
__device__ __forceinline__ void tanh_sech2(float a, float& h, float& g) {
    float ac = fminf(fmaxf(a, -15.f), 15.f);
    float E = __expf(2.f * ac);                 // e^{2a}
    float inv = __builtin_amdgcn_rcpf(E + 1.f); // 1/(e^{2a}+1)
    h = 1.f - 2.f * inv;                        // tanh(a)
    g = 4.f * E * inv * inv;                    // sech^2(a) = 1 - h^2
}

// matvec: weights from swizzled LDS (1 v_xor + 1 ds_read_b128/step),
// state broadcast from per-wave LDS slice (uniform-address reads).
#define MATVEC(WOFF, bj)                                                        \
    av = (bj); ax = 0.f; ay = 0.f; az = 0.f; as_ = 0.f;                         \
    _Pragma("unroll")                                                           \
    for (int ib = 0; ib < 16; ++ib) {                                           \
        const float4 w  = *(const float4*)(wp + (WOFF) + (boff ^ (ib << 4)));   \
        const float4 hv = *(const float4*)(sp + ib * 4);                        \
        const float4 xv = *(const float4*)(sp + 64 + ib * 4);                   \
        const float4 yv = *(const float4*)(sp + 128 + ib * 4);                  \
        const float4 zv = *(const float4*)(sp + 192 + ib * 4);                  \
        const float4 sv = *(const float4*)(sp + 256 + ib * 4);                  \
        av += hv.x*w.x + hv.y*w.y + hv.z*w.z + hv.w*w.w;                        \
        ax += xv.x*w.x + xv.y*w.y + xv.z*w.z + xv.w*w.w;                        \
        ay += yv.x*w.x + yv.y*w.y + yv.z*w.z + yv.w*w.w;                        \
        az += zv.x*w.x + zv.y*w.y + zv.z*w.z + zv.w*w.w;                        \
        as_ += sv.x*w.x + sv.y*w.y + sv.z*w.z + sv.w*w.w;                       \
    }

__global__ __launch_bounds__(256, 4) void pinn_div_kernel(
    const float* __restrict__ x_r, const float* __restrict__ sigma_r,
    const float* __restrict__ W1, const float* __restrict__ b1,
    const float* __restrict__ W2, const float* __restrict__ b2,
    const float* __restrict__ W3, const float* __restrict__ b3,
    const float* __restrict__ W4, float* __restrict__ out)
{
    // Swizzled transposed weights, block-shared:
    //   Wt[s][j][ ((i>>2) ^ (j&15))*4 + (i&3) ] = Ws[i][j]
    // Read addr for i-group ib: (j*256 + ((j&15)<<4)) ^ (ib<<4)  -> 16B aligned,
    // 8 lanes/bank * 32 banks = exactly the 1024B/wave LDS BW floor.
    __shared__ float Wt[2][64][64];   // 32 KB
    __shared__ float st[WPB][5][64];  // 5 KB, per-wave slices (no barriers needed)

    const int lane = threadIdx.x & 63;
    const int wv   = threadIdx.x >> 6;
    const int m    = lane & 15;

    // ---- one-time staging: coalesced global rows -> swizzled LDS ----
    for (int rr = 0; rr < 16; ++rr) {
        const int i   = wv * 16 + rr;
        const int idx = (((i >> 2) ^ m) << 2) | (i & 3);
        Wt[0][lane][idx] = W2[i * 64 + lane];
        Wt[1][lane][idx] = W3[i * 64 + lane];
    }

    const float w1x = W1[lane], w1y = W1[64 + lane], w1z = W1[128 + lane];
    const float b1j = b1[lane], b2j = b2[lane], b3j = b3[lane];
    const float w4j = W4[lane];
    const float q1  = w1x * w1x + w1y * w1y + w1z * w1z;  // sum_d (a1'_d)^2
    __syncthreads();  // weights visible to all waves; the ONLY barrier

    const char*  wp   = (const char*)&Wt[0][0][0];
    const float* sp   = &st[wv][0][0];
    const int    boff = lane * 256 + (m << 4);

    const long sbase = ((long)blockIdx.x * WPB + wv) * SPW;

    for (int t = 0; t < SPW; ++t) {
        const long s = sbase + t;
        const float x0 = x_r[s * 3 + 0];
        const float x1 = x_r[s * 3 + 1];
        const float x2 = x_r[s * 3 + 2];
        const float sg = sigma_r[s];

        // ---- layer 1 (input dim 3; a1'_d = W1[d,:], a1'' = 0) ----
        float h, g;
        tanh_sech2(x0 * w1x + x1 * w1y + x2 * w1z + b1j, h, g);
        float dx = g * w1x, dy = g * w1y, dz = g * w1z;
        float ss = -2.f * h * g * q1;

        float av, ax, ay, az, as_;

        // ---- layer 2 ---- (intra-wave LDS RAW: lgkmcnt ordering, no barrier)
        st[wv][0][lane] = h;  st[wv][1][lane] = dx; st[wv][2][lane] = dy;
        st[wv][3][lane] = dz; st[wv][4][lane] = ss;
        MATVEC(0, b2j);
        tanh_sech2(av, h, g);
        dx = g * ax; dy = g * ay; dz = g * az;
        ss = g * as_ - 2.f * h * g * (ax * ax + ay * ay + az * az);

        // ---- layer 3 ----
        st[wv][0][lane] = h;  st[wv][1][lane] = dx; st[wv][2][lane] = dy;
        st[wv][3][lane] = dz; st[wv][4][lane] = ss;
        MATVEC(16384, b3j);
        tanh_sech2(av, h, g);
        ss = g * as_ - 2.f * h * g * (ax * ax + ay * ay + az * az);

        // ---- output: sigma * (s3 . W4) ----
        float c = ss * w4j;
        c += __shfl_xor(c, 32);
        c += __shfl_xor(c, 16);
        c += __shfl_xor(c, 8);
        c += __shfl_xor(c, 4);
        c += __shfl_xor(c, 2);
        c += __shfl_xor(c, 1);
        if (lane == 0) out[s] = sg * c;
    }
}

extern "C" void kernel_launch(void* const* d_in, const int* in_sizes, int n_in,
                              void* d_out, int out_size, void* d_ws, size_t ws_size,
                              hipStream_t stream) {
    const float* x_r     = (const float*)d_in[0];
    const float* sigma_r = (const float*)d_in[1];
    const float* W1      = (const float*)d_in[2];
    const float* b1      = (const float*)d_in[3];
    const float* W2      = (const float*)d_in[4];
    const float* b2      = (const float*)d_in[5];
    const float* W3      = (const float*)d_in[6];
    const float* b3      = (const float*)d_in[7];
    const float* W4      = (const float*)d_in[8];
    float* out = (float*)d_out;

    pinn_div_kernel<<<NBLOCKS, 256, 0, stream>>>(
        x_r, sigma_r, W1, b1, W2, b2, W3, b3, W4, out);
}

// Round 3
// 49.898 us; speedup vs baseline: 9.2310x; 7.9807x over previous
//
#include <hip/hip_runtime.h>

typedef __fp16 f16;
typedef f16  h8 __attribute__((ext_vector_type(8)));
typedef float f4 __attribute__((ext_vector_type(4)));

#define WPB 4
#define SPW 16
#define BTOT 262144
#define NBLOCKS (BTOT / (WPB * SPW))   // 4096

union H8u { h8 v; unsigned u[4]; };

// pack two f32 -> 2x f16 in one VGPR
__device__ __forceinline__ unsigned pk2(float a, float b) {
    return __builtin_bit_cast(unsigned, __builtin_amdgcn_cvt_pkrtz(a, b));
}

// tanh(a) and sech^2(a) from one exp + one rcp, saturation-safe.
__device__ __forceinline__ void tanh_sech2(float a, float& h, float& g) {
    float ac = fminf(fmaxf(a, -15.f), 15.f);
    float E = __expf(2.f * ac);
    float inv = __builtin_amdgcn_rcpf(E + 1.f);
    h = 1.f - 2.f * inv;
    g = 4.f * E * inv * inv;
}

__global__ __launch_bounds__(256, 2) void pinn_mfma_kernel(
    const float* __restrict__ x_r, const float* __restrict__ sigma_r,
    const float* __restrict__ W1, const float* __restrict__ b1,
    const float* __restrict__ W2, const float* __restrict__ b2,
    const float* __restrict__ W3, const float* __restrict__ b3,
    const float* __restrict__ W4, float* __restrict__ out)
{
    __shared__ f4 Wp[64];                 // (w1x, w1y, w1z, b1) per unit
    __shared__ float Q1l[64];             // w1x^2+w1y^2+w1z^2
    __shared__ f4 B2l[16], B3l[16], W4l[16];
    __shared__ __align__(16) float xch[WPB][2][16 * 68];  // per-wave exchange, stride 68

    const int tid  = threadIdx.x;
    const int lane = tid & 63;
    const int wv   = tid >> 6;
    const int sb   = lane & 15;   // sample slot (B/C col) == A row m
    const int q    = lane >> 4;   // lane quarter -> k-chunk / C row group

    if (tid < 64) {
        float wx = W1[tid], wy = W1[64 + tid], wz = W1[128 + tid];
        f4 w; w[0] = wx; w[1] = wy; w[2] = wz; w[3] = b1[tid];
        Wp[tid] = w;
        Q1l[tid] = wx * wx + wy * wy + wz * wz;
        ((float*)B2l)[tid] = b2[tid];
        ((float*)B3l)[tid] = b3[tid];
        ((float*)W4l)[tid] = W4[tid];
    }
    __syncthreads();   // the only barrier

    // ---- A-fragments: W^T tiles in f16. A[m][k] = W[32kk+8q+e][16mt+sb] ----
    h8 A2f[4][2], A3f[4][2];
#pragma unroll
    for (int mt = 0; mt < 4; ++mt)
#pragma unroll
    for (int kk = 0; kk < 2; ++kk) {
        H8u t2, t3;
#pragma unroll
        for (int p = 0; p < 4; ++p) {
            const int r0 = (32 * kk + 8 * q + 2 * p) * 64 + 16 * mt + sb;
            t2.u[p] = pk2(W2[r0], W2[r0 + 64]);
            t3.u[p] = pk2(W3[r0], W3[r0 + 64]);
        }
        A2f[mt][kk] = t2.v; A3f[mt][kk] = t3.v;
    }

    const long s = ((long)blockIdx.x * WPB + wv) * SPW + sb;
    const float x0 = x_r[s * 3], x1 = x_r[s * 3 + 1], x2 = x_r[s * 3 + 2];
    const float sg = sigma_r[s];

    // ---- layer 1 directly into B-fragments: B[k][n], k = 32kk+8q+e = unit ----
    h8 Bh[2], Bx[2], By[2], Bz[2], Bs[2];
#pragma unroll
    for (int kk = 0; kk < 2; ++kk) {
        H8u th, tx, ty, tz, ts;
#pragma unroll
        for (int p = 0; p < 4; ++p) {
            float hv[2], xv[2], yv[2], zv[2], sv[2];
#pragma unroll
            for (int o = 0; o < 2; ++o) {
                const int u = 32 * kk + 8 * q + 2 * p + o;
                f4 w = Wp[u];
                float a = fmaf(w[0], x0, fmaf(w[1], x1, fmaf(w[2], x2, w[3])));
                float h, g; tanh_sech2(a, h, g);
                hv[o] = h; xv[o] = g * w[0]; yv[o] = g * w[1]; zv[o] = g * w[2];
                sv[o] = -2.f * h * g * Q1l[u];
            }
            th.u[p] = pk2(hv[0], hv[1]); tx.u[p] = pk2(xv[0], xv[1]);
            ty.u[p] = pk2(yv[0], yv[1]); tz.u[p] = pk2(zv[0], zv[1]);
            ts.u[p] = pk2(sv[0], sv[1]);
        }
        Bh[kk] = th.v; Bx[kk] = tx.v; By[kk] = ty.v; Bz[kk] = tz.v; Bs[kk] = ts.v;
    }

    // ---- layer 2 MFMA: C[unit][sample] = W2^T x states^T ----
    f4 Ch[4], Cx[4], Cy[4], Cz[4], Cs[4];
#pragma unroll
    for (int mt = 0; mt < 4; ++mt) {
        Ch[mt] = (f4){0.f,0.f,0.f,0.f}; Cx[mt] = (f4){0.f,0.f,0.f,0.f};
        Cy[mt] = (f4){0.f,0.f,0.f,0.f}; Cz[mt] = (f4){0.f,0.f,0.f,0.f};
        Cs[mt] = (f4){0.f,0.f,0.f,0.f};
    }
#pragma unroll
    for (int mt = 0; mt < 4; ++mt)
#pragma unroll
    for (int kk = 0; kk < 2; ++kk) {
        Ch[mt] = __builtin_amdgcn_mfma_f32_16x16x32_f16(A2f[mt][kk], Bh[kk], Ch[mt], 0, 0, 0);
        Cx[mt] = __builtin_amdgcn_mfma_f32_16x16x32_f16(A2f[mt][kk], Bx[kk], Cx[mt], 0, 0, 0);
        Cy[mt] = __builtin_amdgcn_mfma_f32_16x16x32_f16(A2f[mt][kk], By[kk], Cy[mt], 0, 0, 0);
        Cz[mt] = __builtin_amdgcn_mfma_f32_16x16x32_f16(A2f[mt][kk], Bz[kk], Cz[mt], 0, 0, 0);
        Cs[mt] = __builtin_amdgcn_mfma_f32_16x16x32_f16(A2f[mt][kk], Bs[kk], Cs[mt], 0, 0, 0);
    }

    // ---- layer-2 nonlinearity in C layout (unit u = 16mt + 4q + r, sample sb) ----
    f4 Oh[4], Ox[4], Oy[4], Oz[4], Os[4];
#pragma unroll
    for (int mt = 0; mt < 4; ++mt) {
        f4 bb = B2l[4 * mt + q];
#pragma unroll
        for (int r = 0; r < 4; ++r) {
            float a = Ch[mt][r] + bb[r];
            float h, g; tanh_sech2(a, h, g);
            float ax = Cx[mt][r], ay = Cy[mt][r], az = Cz[mt][r];
            Oh[mt][r] = h; Ox[mt][r] = g * ax; Oy[mt][r] = g * ay; Oz[mt][r] = g * az;
            Os[mt][r] = fmaf(g, Cs[mt][r], -2.f * h * g * (ax * ax + ay * ay + az * az));
        }
    }

    // ---- exchange: C layout -> B-frags via per-wave LDS (in-order DS, no barrier).
    // row = sample (stride 68 f32 = 17 f4, spreads banks), col = unit.
    f4* xb0 = (f4*)&xch[wv][0][0];
    f4* xb1 = (f4*)&xch[wv][1][0];
    const int wo = sb * 17 + q;        // write slot; +4 per mt
    const int ro = sb * 17 + 2 * q;    // read slot; kk=1 -> +8

#define XWR(bufp, O) { bufp[wo] = O[0]; bufp[wo + 4] = O[1]; bufp[wo + 8] = O[2]; bufp[wo + 12] = O[3]; }
#define XRD(bufp, Bf) { f4 r0 = bufp[ro], r1 = bufp[ro + 1], r2 = bufp[ro + 8], r3 = bufp[ro + 9]; \
        H8u t0, t1; \
        t0.u[0] = pk2(r0[0], r0[1]); t0.u[1] = pk2(r0[2], r0[3]); \
        t0.u[2] = pk2(r1[0], r1[1]); t0.u[3] = pk2(r1[2], r1[3]); \
        t1.u[0] = pk2(r2[0], r2[1]); t1.u[1] = pk2(r2[2], r2[3]); \
        t1.u[2] = pk2(r3[0], r3[1]); t1.u[3] = pk2(r3[2], r3[3]); \
        Bf[0] = t0.v; Bf[1] = t1.v; }

    XWR(xb0, Oh)
    XWR(xb1, Ox)
    XRD(xb0, Bh)
    XWR(xb0, Oy)      // overwrites Oh slots; DS in-order: Bh reads already executed
    XRD(xb1, Bx)
    XWR(xb1, Oz)
    XRD(xb0, By)
    XWR(xb0, Os)
    XRD(xb1, Bz)
    XRD(xb0, Bs)

    // ---- layer 3 MFMA ----
#pragma unroll
    for (int mt = 0; mt < 4; ++mt) {
        Ch[mt] = (f4){0.f,0.f,0.f,0.f}; Cx[mt] = (f4){0.f,0.f,0.f,0.f};
        Cy[mt] = (f4){0.f,0.f,0.f,0.f}; Cz[mt] = (f4){0.f,0.f,0.f,0.f};
        Cs[mt] = (f4){0.f,0.f,0.f,0.f};
    }
#pragma unroll
    for (int mt = 0; mt < 4; ++mt)
#pragma unroll
    for (int kk = 0; kk < 2; ++kk) {
        Ch[mt] = __builtin_amdgcn_mfma_f32_16x16x32_f16(A3f[mt][kk], Bh[kk], Ch[mt], 0, 0, 0);
        Cx[mt] = __builtin_amdgcn_mfma_f32_16x16x32_f16(A3f[mt][kk], Bx[kk], Cx[mt], 0, 0, 0);
        Cy[mt] = __builtin_amdgcn_mfma_f32_16x16x32_f16(A3f[mt][kk], By[kk], Cy[mt], 0, 0, 0);
        Cz[mt] = __builtin_amdgcn_mfma_f32_16x16x32_f16(A3f[mt][kk], Bz[kk], Cz[mt], 0, 0, 0);
        Cs[mt] = __builtin_amdgcn_mfma_f32_16x16x32_f16(A3f[mt][kk], Bs[kk], Cs[mt], 0, 0, 0);
    }

    // ---- layer-3 nonlinearity + output dot with W4 ----
    float tot = 0.f;
#pragma unroll
    for (int mt = 0; mt < 4; ++mt) {
        f4 bb = B3l[4 * mt + q], w4v = W4l[4 * mt + q];
#pragma unroll
        for (int r = 0; r < 4; ++r) {
            float a = Ch[mt][r] + bb[r];
            float h, g; tanh_sech2(a, h, g);
            float ax = Cx[mt][r], ay = Cy[mt][r], az = Cz[mt][r];
            float sv = fmaf(g, Cs[mt][r], -2.f * h * g * (ax * ax + ay * ay + az * az));
            tot = fmaf(sv, w4v[r], tot);
        }
    }
    tot += __shfl_xor(tot, 16);   // sum q pairs
    tot += __shfl_xor(tot, 32);   // sum q quads
    if (lane < 16) out[s] = sg * tot;
}

extern "C" void kernel_launch(void* const* d_in, const int* in_sizes, int n_in,
                              void* d_out, int out_size, void* d_ws, size_t ws_size,
                              hipStream_t stream) {
    const float* x_r     = (const float*)d_in[0];
    const float* sigma_r = (const float*)d_in[1];
    const float* W1      = (const float*)d_in[2];
    const float* b1      = (const float*)d_in[3];
    const float* W2      = (const float*)d_in[4];
    const float* b2      = (const float*)d_in[5];
    const float* W3      = (const float*)d_in[6];
    const float* b3      = (const float*)d_in[7];
    const float* W4      = (const float*)d_in[8];
    float* out = (float*)d_out;

    pinn_mfma_kernel<<<NBLOCKS, 256, 0, stream>>>(
        x_r, sigma_r, W1, b1, W2, b2, W3, b3, W4, out);
}

// Round 4
// 44.141 us; speedup vs baseline: 10.4349x; 1.1304x over previous
//
#include <hip/hip_runtime.h>

typedef __fp16 f16;
typedef f16  h8 __attribute__((ext_vector_type(8)));
typedef float f4 __attribute__((ext_vector_type(4)));
typedef unsigned u32t;

#define NBLOCKS 1024
#define WPB 4
#define SPW 64                 // samples per wave
#define NBATCH 4               // SPW / 16
#define XSTR 36                // u32 per sample row (even, 16B-aligned rows)
#define XST  (16 * XSTR)       // u32 per state

union H8u { h8 v; u32t u[4]; };
union U4h { uint4 u; h8 v; };

__device__ __forceinline__ u32t pk2(float a, float b) {
    return __builtin_bit_cast(u32t, __builtin_amdgcn_cvt_pkrtz(a, b));
}

// clamp-free tanh + sech^2: E=inf -> h=1,g=0 ; E=0 -> h=-1,g=0 (no NaN)
__device__ __forceinline__ void tanh_sech2(float a, float& h, float& g) {
    float E = __expf(2.f * a);
    float inv = __builtin_amdgcn_rcpf(E + 1.f);
    float u = inv + inv;
    h = 1.f - u;                 // tanh(a)
    g = u * (2.f - u);           // sech^2(a)
}

__global__ __launch_bounds__(256, 3) void pinn_mfma_kernel(
    const float* __restrict__ x_r, const float* __restrict__ sigma_r,
    const float* __restrict__ W1, const float* __restrict__ b1,
    const float* __restrict__ W2, const float* __restrict__ b2,
    const float* __restrict__ W3, const float* __restrict__ b3,
    const float* __restrict__ W4, float* __restrict__ out)
{
    __shared__ f4 Wg[64];                   // (w1x, w1y, w1z, -2*Q1) per unit
    __shared__ f4 Wb4[16], B2v[16], B3v[16], W4v[16];
    __shared__ u32t xch[WPB][5 * XST];      // f16-pair exchange, 46 KB

    const int tid = threadIdx.x, lane = tid & 63, wv = tid >> 6;
    const int sb = lane & 15;   // sample slot (B/C col)
    const int q  = lane >> 4;   // lane quarter (C row group / B k-chunk)

    if (tid < 64) {
        float wx = W1[tid], wy = W1[64 + tid], wz = W1[128 + tid];
        f4 w; w[0] = wx; w[1] = wy; w[2] = wz;
        w[3] = -2.f * (wx * wx + wy * wy + wz * wz);
        Wg[tid] = w;
        ((float*)Wb4)[tid] = b1[tid];
        ((float*)B2v)[tid] = b2[tid];
        ((float*)B3v)[tid] = b3[tid];
        ((float*)W4v)[tid] = W4[tid];
    }
    __syncthreads();   // the only barrier

    // ---- A-fragments (validated mapping): A[m][k] = W[32kk+8q+e][16mt+sb] ----
    h8 A2f[4][2], A3f[4][2];
#pragma unroll
    for (int mt = 0; mt < 4; ++mt)
#pragma unroll
    for (int kk = 0; kk < 2; ++kk) {
        H8u t2, t3;
#pragma unroll
        for (int p = 0; p < 4; ++p) {
            const int r0 = (32 * kk + 8 * q + 2 * p) * 64 + 16 * mt + sb;
            t2.u[p] = pk2(W2[r0], W2[r0 + 64]);
            t3.u[p] = pk2(W3[r0], W3[r0 + 64]);
        }
        A2f[mt][kk] = t2.v; A3f[mt][kk] = t3.v;
    }

    u32t* xb = xch[wv];
    const int wbase = sb * XSTR + 2 * q;   // + 8*mt + st*XST   (b64 writes)
    const int rbase = sb * XSTR + 4 * q;   // + 16*kk + st*XST  (b128 reads)

    const long sbase = ((long)blockIdx.x * WPB + wv) * SPW;

    // prefetch batch 0
    float nx0 = x_r[(sbase + sb) * 3], nx1 = x_r[(sbase + sb) * 3 + 1],
          nx2 = x_r[(sbase + sb) * 3 + 2], nsg = sigma_r[sbase + sb];

#define WR5(mt) { const int wo = wbase + 8 * (mt);                                         \
    *(uint2*)&xb[0 * XST + wo] = make_uint2(pk2(oh[0], oh[1]), pk2(oh[2], oh[3]));         \
    *(uint2*)&xb[1 * XST + wo] = make_uint2(pk2(ox[0], ox[1]), pk2(ox[2], ox[3]));         \
    *(uint2*)&xb[2 * XST + wo] = make_uint2(pk2(oy[0], oy[1]), pk2(oy[2], oy[3]));         \
    *(uint2*)&xb[3 * XST + wo] = make_uint2(pk2(oz[0], oz[1]), pk2(oz[2], oz[3]));         \
    *(uint2*)&xb[4 * XST + wo] = make_uint2(pk2(os[0], os[1]), pk2(os[2], os[3])); }

#define RDB(Bf, st) { U4h u0, u1;                                                          \
    u0.u = *(const uint4*)&xb[(st) * XST + rbase];                                         \
    u1.u = *(const uint4*)&xb[(st) * XST + rbase + 16];                                    \
    Bf[0] = u0.v; Bf[1] = u1.v; }

#define MFMA10(Af) _Pragma("unroll")                                                       \
    for (int kk = 0; kk < 2; ++kk) {                                                       \
        Ch = __builtin_amdgcn_mfma_f32_16x16x32_f16(Af[mt][kk], Bh[kk], Ch, 0, 0, 0);      \
        Cx = __builtin_amdgcn_mfma_f32_16x16x32_f16(Af[mt][kk], Bx[kk], Cx, 0, 0, 0);      \
        Cy = __builtin_amdgcn_mfma_f32_16x16x32_f16(Af[mt][kk], By[kk], Cy, 0, 0, 0);      \
        Cz = __builtin_amdgcn_mfma_f32_16x16x32_f16(Af[mt][kk], Bz[kk], Cz, 0, 0, 0);      \
        Cs = __builtin_amdgcn_mfma_f32_16x16x32_f16(Af[mt][kk], Bs[kk], Cs, 0, 0, 0);      \
    }

#pragma unroll 1
    for (int t = 0; t < NBATCH; ++t) {
        const float x0 = nx0, x1 = nx1, x2 = nx2, sg = nsg;
        const long sn = sbase + ((t + 1) & 3) * 16 + sb;   // wraps on last iter (benign)
        nx0 = x_r[sn * 3]; nx1 = x_r[sn * 3 + 1]; nx2 = x_r[sn * 3 + 2];
        nsg = sigma_r[sn];

        // ---- layer 1 in C layout (a = W1.x + b1; derivs from Wg), pack, write ----
#pragma unroll
        for (int mt = 0; mt < 4; ++mt) {
            const f4 bb = Wb4[4 * mt + q];
            float oh[4], ox[4], oy[4], oz[4], os[4];
#pragma unroll
            for (int r = 0; r < 4; ++r) {
                const f4 w = Wg[16 * mt + 4 * q + r];
                float a = fmaf(w[0], x0, fmaf(w[1], x1, fmaf(w[2], x2, bb[r])));
                float h, g; tanh_sech2(a, h, g);
                oh[r] = h; ox[r] = g * w[0]; oy[r] = g * w[1]; oz[r] = g * w[2];
                os[r] = (h * g) * w[3];               // -2*h*g*Q1
            }
            WR5(mt)
        }

        // ---- B-fragments for layer 2 (in-order DS: reads after writes) ----
        h8 Bh[2], Bx[2], By[2], Bz[2], Bs[2];
        RDB(Bh, 0) RDB(Bx, 1) RDB(By, 2) RDB(Bz, 3) RDB(Bs, 4)

        // ---- layer 2: per-mt MFMA -> NL -> pack -> write ----
#pragma unroll
        for (int mt = 0; mt < 4; ++mt) {
            f4 Ch = {0.f,0.f,0.f,0.f}, Cx = {0.f,0.f,0.f,0.f}, Cy = {0.f,0.f,0.f,0.f},
               Cz = {0.f,0.f,0.f,0.f}, Cs = {0.f,0.f,0.f,0.f};
            MFMA10(A2f)
            const f4 bb = B2v[4 * mt + q];
            float oh[4], ox[4], oy[4], oz[4], os[4];
#pragma unroll
            for (int r = 0; r < 4; ++r) {
                float h, g; tanh_sech2(Ch[r] + bb[r], h, g);
                float ax = Cx[r], ay = Cy[r], az = Cz[r];
                float qq  = fmaf(ax, ax, fmaf(ay, ay, az * az));
                float hg2 = (h * g) * 2.f;
                oh[r] = h; ox[r] = g * ax; oy[r] = g * ay; oz[r] = g * az;
                os[r] = fmaf(g, Cs[r], -(hg2 * qq));
            }
            WR5(mt)
        }

        // ---- B-fragments for layer 3 ----
        RDB(Bh, 0) RDB(Bx, 1) RDB(By, 2) RDB(Bz, 3) RDB(Bs, 4)

        // ---- layer 3: per-mt MFMA -> NL -> dot with W4 ----
        float tot = 0.f;
#pragma unroll
        for (int mt = 0; mt < 4; ++mt) {
            f4 Ch = {0.f,0.f,0.f,0.f}, Cx = {0.f,0.f,0.f,0.f}, Cy = {0.f,0.f,0.f,0.f},
               Cz = {0.f,0.f,0.f,0.f}, Cs = {0.f,0.f,0.f,0.f};
            MFMA10(A3f)
            const f4 bb = B3v[4 * mt + q], w4 = W4v[4 * mt + q];
#pragma unroll
            for (int r = 0; r < 4; ++r) {
                float h, g; tanh_sech2(Ch[r] + bb[r], h, g);
                float ax = Cx[r], ay = Cy[r], az = Cz[r];
                float qq  = fmaf(ax, ax, fmaf(ay, ay, az * az));
                float hg2 = (h * g) * 2.f;
                float sv  = fmaf(g, Cs[r], -(hg2 * qq));
                tot = fmaf(sv, w4[r], tot);
            }
        }
        tot += __shfl_xor(tot, 16);
        tot += __shfl_xor(tot, 32);
        if (lane < 16) out[sbase + t * 16 + sb] = sg * tot;
    }
}

extern "C" void kernel_launch(void* const* d_in, const int* in_sizes, int n_in,
                              void* d_out, int out_size, void* d_ws, size_t ws_size,
                              hipStream_t stream) {
    const float* x_r     = (const float*)d_in[0];
    const float* sigma_r = (const float*)d_in[1];
    const float* W1      = (const float*)d_in[2];
    const float* b1      = (const float*)d_in[3];
    const float* W2      = (const float*)d_in[4];
    const float* b2      = (const float*)d_in[5];
    const float* W3      = (const float*)d_in[6];
    const float* b3      = (const float*)d_in[7];
    const float* W4      = (const float*)d_in[8];
    float* out = (float*)d_out;

    pinn_mfma_kernel<<<NBLOCKS, 256, 0, stream>>>(
        x_r, sigma_r, W1, b1, W2, b2, W3, b3, W4, out);
}